// Round 6
// baseline (981.654 us; speedup 1.0000x reference)
//
#include <hip/hip_runtime.h>
#include <hip/hip_bf16.h>

#define N_NODES 100000
#define N_EDGES 3200000
#define KITER   10
#define ALPHA   0.1f

#define SCAN_BS 512
#define SCAN_NB ((N_NODES + SCAN_BS - 1) / SCAN_BS)   // 196

typedef __attribute__((ext_vector_type(4))) float f32x4;
typedef __attribute__((ext_vector_type(8))) short bf16x8;
typedef unsigned short u16;

__device__ inline float bf2f(u16 u) {
    unsigned int x = ((unsigned int)u) << 16;
    return __uint_as_float(x);
}
__device__ inline float bf2f_lo(unsigned int w) { return __uint_as_float(w << 16); }
__device__ inline float bf2f_hi(unsigned int w) { return __uint_as_float(w & 0xffff0000u); }
__device__ inline u16 f2bf(float f) {
    __hip_bfloat16 h = __float2bfloat16(f);
    return *reinterpret_cast<u16*>(&h);
}
__device__ inline bf16x8 cvt8(float4 lo, float4 hi) {
    bf16x8 r;
    r[0] = (short)f2bf(lo.x); r[1] = (short)f2bf(lo.y);
    r[2] = (short)f2bf(lo.z); r[3] = (short)f2bf(lo.w);
    r[4] = (short)f2bf(hi.x); r[5] = (short)f2bf(hi.y);
    r[6] = (short)f2bf(hi.z); r[7] = (short)f2bf(hi.w);
    return r;
}

// edge_index may arrive as int64 (reference dtype) or int32 (harness policy).
__global__ void k_detect(const unsigned int* e32, int* flag) {
    if (threadIdx.x == 0) {
        int is64 = 1;
        for (int i = 0; i < 64; ++i)
            if (e32[2 * i + 1] != 0u) { is64 = 0; break; }
        *flag = is64;
    }
}

__device__ inline int eidx(const void* p, int is64, int i) {
    if (is64) return (int)((const long long*)p)[i];
    return ((const int*)p)[i];
}

// convert edges to int32 row/col arrays AND count in-degrees (fused)
__global__ void k_convert_count(const void* edges, const int* flag,
                                int* row32, int* col32, int* deg) {
    int i = blockIdx.x * 256 + threadIdx.x;
    if (i >= N_EDGES) return;
    int is64 = *flag;
    int r = eidx(edges, is64, i);
    int c = eidx(edges, is64, N_EDGES + i);
    row32[i] = r;
    col32[i] = c;
    atomicAdd(&deg[c], 1);
}

// ---- two-level scan: local scan -> scan of block sums -> apply ----
__global__ __launch_bounds__(SCAN_BS) void k_scan_part(const int* __restrict__ deg,
                                                       int* __restrict__ ptr,
                                                       int* __restrict__ bsum) {
    __shared__ int lds[SCAN_BS];
    int t = threadIdx.x;
    int idx = blockIdx.x * SCAN_BS + t;
    int s = (idx < N_NODES) ? deg[idx] : 0;
    lds[t] = s;
    __syncthreads();
#pragma unroll
    for (int off = 1; off < SCAN_BS; off <<= 1) {
        int v = (t >= off) ? lds[t - off] : 0;
        __syncthreads();
        lds[t] += v;
        __syncthreads();
    }
    if (idx < N_NODES) ptr[idx] = lds[t] - s;     // exclusive local
    if (t == SCAN_BS - 1) bsum[blockIdx.x] = lds[t];
}

__global__ __launch_bounds__(256) void k_scan_bsum(const int* __restrict__ bsum,
                                                   int* __restrict__ boff,
                                                   int* __restrict__ ptr) {
    __shared__ int lds[256];
    int t = threadIdx.x;
    int s = (t < SCAN_NB) ? bsum[t] : 0;
    lds[t] = s;
    __syncthreads();
#pragma unroll
    for (int off = 1; off < 256; off <<= 1) {
        int v = (t >= off) ? lds[t - off] : 0;
        __syncthreads();
        lds[t] += v;
        __syncthreads();
    }
    if (t < SCAN_NB) boff[t] = lds[t] - s;        // exclusive
    if (t == 255) ptr[N_NODES] = lds[t];          // total (== N_EDGES)
}

__global__ __launch_bounds__(SCAN_BS) void k_scan_apply(const int* __restrict__ deg,
                                                        const int* __restrict__ boff,
                                                        int* __restrict__ ptr,
                                                        int* __restrict__ cursor,
                                                        float* __restrict__ dinv) {
    int idx = blockIdx.x * SCAN_BS + threadIdx.x;
    if (idx >= N_NODES) return;
    int p = ptr[idx] + boff[blockIdx.x];
    ptr[idx] = p;
    cursor[idx] = p;
    dinv[idx] = rsqrtf((float)(deg[idx] + 1));    // +1 self loop
}

// XCD-ownership fill: grp = blockIdx%8 owns target range [grp*12500, +12500).
#define FILL_SLICES 128
__global__ __launch_bounds__(256) void k_fill2(const int* __restrict__ row32,
                                               const int* __restrict__ col32,
                                               int* cursor, int* __restrict__ csr_src) {
    int b = blockIdx.x;
    int grp = b & 7;
    int slice = b >> 3;
    int lo = grp * 12500, hi = lo + 12500;
    const int per = (N_EDGES + FILL_SLICES - 1) / FILL_SLICES;  // 25000
    int e0 = slice * per;
    int e1 = min(N_EDGES, e0 + per);
    for (int e = e0 + (int)threadIdx.x; e < e1; e += 256) {
        int c = col32[e];
        if (c >= lo && c < hi) {
            int r = row32[e];
            int p = atomicAdd(&cursor[c], 1);
            csr_src[p] = r;
        }
    }
}

// W1 [500,256] f32 -> W1s bf16 swizzled [ks=16][n=256][kk=32], K zero-padded to 512
__global__ void k_wconv1(const float* W1, u16* W1s) {
    int idx = blockIdx.x * 256 + threadIdx.x;
    if (idx >= 16 * 256 * 32) return;
    int ks = idx / (256 * 32);
    int rem = idx % (256 * 32);
    int n = rem / 32, kk = rem % 32;
    int k = ks * 32 + kk;
    float v = (k < 500) ? W1[k * 256 + n] : 0.0f;
    W1s[idx] = f2bf(v);
}

// W2 [256,64] f32 -> W2s bf16 swizzled [ks=8][n=64][kk=32]
__global__ void k_wconv2(const float* W2, u16* W2s) {
    int idx = blockIdx.x * 256 + threadIdx.x;
    if (idx >= 8 * 64 * 32) return;
    int ks = idx / (64 * 32);
    int rem = idx % (64 * 32);
    int n = rem / 32, kk = rem % 32;
    int k = ks * 32 + kk;
    W2s[idx] = f2bf(W2[k * 64 + n]);
}

// Fused MLP v4: 16 rows/WAVE (acc = 64 AGPR), 64 rows/block, depth-2 x ring.
// Small per-wave state -> 3 waves/SIMD resident; cross-wave overlap covers the
// per-step vmcnt latency equilibrium (~450cy) that defeated deeper rings.
#define MLP_ROWS 64
#define HSTR 264    // u16 stride for H rows
#define H2STR 72    // u16 stride for pack buffer (16B-aligned rows)

__global__ __launch_bounds__(256, 3) void k_mlp(
    const float* __restrict__ x, const u16* __restrict__ W1s,
    const float* __restrict__ b1, const u16* __restrict__ W2s,
    const float* __restrict__ b2, const float* __restrict__ dinv,
    u16* __restrict__ h_bf, u16* __restrict__ zs0) {

    __shared__ u16 H_lds[MLP_ROWS * HSTR];   // 33792 B

    int t = threadIdx.x;
    int lane = t & 63, w = t >> 6;
    int m0 = blockIdx.x * MLP_ROWS;
    int cl = lane & 15, hi = lane >> 4;

    int row = m0 + w * 16 + cl;               // wave w owns rows m0+16w..+15
    int rowc = min(row, N_NODES - 1);
    const float* xr = x + (size_t)rowc * 500 + 8 * hi;
    const size_t XMAX = (size_t)N_NODES * 500 - 4;  // last valid float4 start

    f32x4 acc[16];
    f32x4 zero = {0.f, 0.f, 0.f, 0.f};
#pragma unroll
    for (int i = 0; i < 16; ++i) acc[i] = zero;

    const u16* bbase = W1s + cl * 32 + 8 * hi;

    // depth-2 prefetch ring
    float4 xs[2][2];
#pragma unroll
    for (int d = 0; d < 2; ++d) {
        xs[d][0] = *(const float4*)(xr + d * 32);
        xs[d][1] = *(const float4*)(xr + d * 32 + 4);
    }

#pragma unroll
    for (int ks = 0; ks < 16; ++ks) {
        const int cur = ks & 1;
        bf16x8 af = cvt8(xs[cur][0], xs[cur][1]);
        if (ks + 2 <= 15) {
            const int kn = ks + 2;
            if (kn == 15) {
                // tail: clamp flat index (W1s zero rows null the k>=500 lanes)
                size_t f0 = (size_t)rowc * 500 + 480 + 8 * hi;
                size_t a0 = f0 > XMAX ? XMAX : f0;
                size_t a1 = (f0 + 4) > XMAX ? XMAX : (f0 + 4);
                xs[cur][0] = *(const float4*)(x + a0);
                xs[cur][1] = *(const float4*)(x + a1);
            } else {
                xs[cur][0] = *(const float4*)(xr + kn * 32);
                xs[cur][1] = *(const float4*)(xr + kn * 32 + 4);
            }
        }
        const u16* bp = bbase + ks * 8192;
#pragma unroll
        for (int nt = 0; nt < 16; ++nt) {
            bf16x8 b = *reinterpret_cast<const bf16x8*>(bp + nt * 512);
            acc[nt] = __builtin_amdgcn_mfma_f32_16x16x32_bf16(af, b, acc[nt], 0, 0, 0);
        }
    }

    // epilogue 1: +b1, relu -> H_lds (wave-private 16 rows; no barrier needed)
    {
        int rl0 = w * 16 + hi * 4;
#pragma unroll
        for (int nt = 0; nt < 16; ++nt) {
            int col = nt * 16 + cl;
            float bb = b1[col];
#pragma unroll
            for (int r = 0; r < 4; ++r) {
                float v0 = fmaxf(acc[nt][r] + bb, 0.0f);
                H_lds[(rl0 + r) * HSTR + col] = f2bf(v0);
            }
        }
    }

    // GEMM2: H[16 rows x 256] @ W2s[256 x 64], B direct from global (L2)
    f32x4 acc2[4];
#pragma unroll
    for (int i = 0; i < 4; ++i) acc2[i] = zero;
    int rA0 = w * 16 + cl;
#pragma unroll
    for (int ks2 = 0; ks2 < 8; ++ks2) {
        bf16x8 af = *reinterpret_cast<const bf16x8*>(&H_lds[rA0 * HSTR + ks2 * 32 + 8 * hi]);
#pragma unroll
        for (int nt = 0; nt < 4; ++nt) {
            bf16x8 b = *reinterpret_cast<const bf16x8*>(W2s + (ks2 * 64 + nt * 16 + cl) * 32 + 8 * hi);
            acc2[nt] = __builtin_amdgcn_mfma_f32_16x16x32_bf16(af, b, acc2[nt], 0, 0, 0);
        }
    }
    __syncthreads();   // all waves done reading H_lds; safe to overwrite as H2

    // epilogue 2: +b2 -> pack buffer H2 (reuses H_lds memory)
    u16* H2 = H_lds;
    {
        int rl0 = w * 16 + hi * 4;
#pragma unroll
        for (int nt = 0; nt < 4; ++nt) {
            int col = nt * 16 + cl;
            float bb = b2[col];
#pragma unroll
            for (int r = 0; r < 4; ++r) {
                H2[(rl0 + r) * H2STR + col] = f2bf(acc2[nt][r] + bb);
            }
        }
    }
    __syncthreads();

    // pack & store: thread t handles a quarter row (16 u16 = 32B), coalesced
    {
        int rl = t >> 2, q = t & 3;
        int grow = m0 + rl;
        if (grow < N_NODES) {
            float dv = dinv[grow];
            const uint4* src = (const uint4*)&H2[rl * H2STR + q * 16];
            uint4 hq[2] = {src[0], src[1]};
            uint4 zq[2];
#pragma unroll
            for (int i = 0; i < 2; ++i) {
                unsigned int* hw = (unsigned int*)&hq[i];
                unsigned int* zw = (unsigned int*)&zq[i];
#pragma unroll
                for (int jj = 0; jj < 4; ++jj) {
                    float lo = dv * bf2f_lo(hw[jj]);
                    float hi2 = dv * bf2f_hi(hw[jj]);
                    zw[jj] = (unsigned)f2bf(lo) | ((unsigned)f2bf(hi2) << 16);
                }
            }
            uint4* hd = (uint4*)(h_bf + (size_t)grow * 64 + q * 16);
            uint4* zd = (uint4*)(zs0 + (size_t)grow * 64 + q * 16);
            hd[0] = hq[0]; hd[1] = hq[1];
            zd[0] = zq[0]; zd[1] = zq[1];
        }
    }
}

// Propagation v3 (unchanged): one wave per node, dwordx4 gathers of 8 edges.
__global__ __launch_bounds__(256) void k_prop3(
    const u16* __restrict__ zs_in, const u16* __restrict__ h_bf,
    const float* __restrict__ dinv, const int* __restrict__ ptr,
    const int* __restrict__ csr_src, u16* __restrict__ zs_out,
    float* __restrict__ out, int last) {

    int lane = threadIdx.x & 63;
    int g = lane >> 3;   // edge slot 0..7
    int c = lane & 7;    // channels 8c..8c+7
    int v = blockIdx.x * 4 + (threadIdx.x >> 6);
    if (v >= N_NODES) return;
    int s0 = ptr[v], s1 = ptr[v + 1];

    float a0 = 0.f, a1 = 0.f, a2 = 0.f, a3 = 0.f;
    float a4 = 0.f, a5 = 0.f, a6 = 0.f, a7 = 0.f;
    float b0 = 0.f, b1 = 0.f, b2 = 0.f, b3 = 0.f;
    float b4 = 0.f, b5 = 0.f, b6 = 0.f, b7 = 0.f;

    for (int base = s0; base < s1; base += 64) {
        int nwin = min(64, s1 - base);
        int ei = base + lane;
        int sv = (ei < s1) ? csr_src[ei] : v;   // fallback: safe address
        int j = 0;
        for (; j + 16 <= nwin; j += 16) {
            int u0 = __shfl(sv, j + g, 64);
            int u1 = __shfl(sv, j + 8 + g, 64);
            uint4 q0 = *(const uint4*)(zs_in + (size_t)u0 * 64 + c * 8);
            uint4 q1 = *(const uint4*)(zs_in + (size_t)u1 * 64 + c * 8);
            a0 += bf2f_lo(q0.x); a1 += bf2f_hi(q0.x);
            a2 += bf2f_lo(q0.y); a3 += bf2f_hi(q0.y);
            a4 += bf2f_lo(q0.z); a5 += bf2f_hi(q0.z);
            a6 += bf2f_lo(q0.w); a7 += bf2f_hi(q0.w);
            b0 += bf2f_lo(q1.x); b1 += bf2f_hi(q1.x);
            b2 += bf2f_lo(q1.y); b3 += bf2f_hi(q1.y);
            b4 += bf2f_lo(q1.z); b5 += bf2f_hi(q1.z);
            b6 += bf2f_lo(q1.w); b7 += bf2f_hi(q1.w);
        }
        for (; j < nwin; j += 8) {
            int idx = j + g;
            int u = __shfl(sv, idx, 64);  // idx<=63; invalid lanes hold v (safe)
            uint4 q = *(const uint4*)(zs_in + (size_t)u * 64 + c * 8);
            if (idx < nwin) {
                a0 += bf2f_lo(q.x); a1 += bf2f_hi(q.x);
                a2 += bf2f_lo(q.y); a3 += bf2f_hi(q.y);
                a4 += bf2f_lo(q.z); a5 += bf2f_hi(q.z);
                a6 += bf2f_lo(q.w); a7 += bf2f_hi(q.w);
            }
        }
    }
    a0 += b0; a1 += b1; a2 += b2; a3 += b3;
    a4 += b4; a5 += b5; a6 += b6; a7 += b7;
#pragma unroll
    for (int off = 8; off <= 32; off <<= 1) {
        a0 += __shfl_xor(a0, off, 64); a1 += __shfl_xor(a1, off, 64);
        a2 += __shfl_xor(a2, off, 64); a3 += __shfl_xor(a3, off, 64);
        a4 += __shfl_xor(a4, off, 64); a5 += __shfl_xor(a5, off, 64);
        a6 += __shfl_xor(a6, off, 64); a7 += __shfl_xor(a7, off, 64);
    }

    float dv = dinv[v];
    uint4 qs = *(const uint4*)(zs_in + (size_t)v * 64 + c * 8);
    uint4 qh = *(const uint4*)(h_bf + (size_t)v * 64 + c * 8);
    float z0 = (1.0f - ALPHA) * dv * (a0 + bf2f_lo(qs.x)) + ALPHA * bf2f_lo(qh.x);
    float z1 = (1.0f - ALPHA) * dv * (a1 + bf2f_hi(qs.x)) + ALPHA * bf2f_hi(qh.x);
    float z2 = (1.0f - ALPHA) * dv * (a2 + bf2f_lo(qs.y)) + ALPHA * bf2f_lo(qh.y);
    float z3 = (1.0f - ALPHA) * dv * (a3 + bf2f_hi(qs.y)) + ALPHA * bf2f_hi(qh.y);
    float z4 = (1.0f - ALPHA) * dv * (a4 + bf2f_lo(qs.z)) + ALPHA * bf2f_lo(qh.z);
    float z5 = (1.0f - ALPHA) * dv * (a5 + bf2f_hi(qs.z)) + ALPHA * bf2f_hi(qh.z);
    float z6 = (1.0f - ALPHA) * dv * (a6 + bf2f_lo(qs.w)) + ALPHA * bf2f_lo(qh.w);
    float z7 = (1.0f - ALPHA) * dv * (a7 + bf2f_hi(qs.w)) + ALPHA * bf2f_hi(qh.w);

    if (!last) {
        if (g == 0) {
            uint4 o;
            o.x = (unsigned)f2bf(dv * z0) | ((unsigned)f2bf(dv * z1) << 16);
            o.y = (unsigned)f2bf(dv * z2) | ((unsigned)f2bf(dv * z3) << 16);
            o.z = (unsigned)f2bf(dv * z4) | ((unsigned)f2bf(dv * z5) << 16);
            o.w = (unsigned)f2bf(dv * z6) | ((unsigned)f2bf(dv * z7) << 16);
            *(uint4*)(zs_out + (size_t)v * 64 + c * 8) = o;
        }
    } else {
        float m = fmaxf(fmaxf(fmaxf(z0, z1), fmaxf(z2, z3)),
                        fmaxf(fmaxf(z4, z5), fmaxf(z6, z7)));
#pragma unroll
        for (int off = 1; off <= 4; off <<= 1) m = fmaxf(m, __shfl_xor(m, off, 64));
        float p = expf(z0 - m) + expf(z1 - m) + expf(z2 - m) + expf(z3 - m)
                + expf(z4 - m) + expf(z5 - m) + expf(z6 - m) + expf(z7 - m);
#pragma unroll
        for (int off = 1; off <= 4; off <<= 1) p += __shfl_xor(p, off, 64);
        float ls = logf(p);
        if (g == 0) {
            float4 o1 = {z0 - m - ls, z1 - m - ls, z2 - m - ls, z3 - m - ls};
            float4 o2 = {z4 - m - ls, z5 - m - ls, z6 - m - ls, z7 - m - ls};
            *(float4*)(out + (size_t)v * 64 + c * 8) = o1;
            *(float4*)(out + (size_t)v * 64 + c * 8 + 4) = o2;
        }
    }
}

extern "C" void kernel_launch(void* const* d_in, const int* in_sizes, int n_in,
                              void* d_out, int out_size, void* d_ws, size_t ws_size,
                              hipStream_t stream) {
    const float* x  = (const float*)d_in[0];
    const void* edges = d_in[1];
    const float* W1 = (const float*)d_in[2];
    const float* b1 = (const float*)d_in[3];
    const float* W2 = (const float*)d_in[4];
    const float* b2 = (const float*)d_in[5];
    float* out = (float*)d_out;

    char* ws = (char*)d_ws;
    size_t off = 0;
    auto alloc = [&](size_t bytes) -> void* {
        void* p = ws + off;
        off = (off + bytes + 255) & ~(size_t)255;
        return p;
    };
    int*   flag    = (int*)alloc(4);
    int*   deg     = (int*)alloc((size_t)N_NODES * 4);
    float* dinv    = (float*)alloc((size_t)N_NODES * 4);
    int*   ptr     = (int*)alloc((size_t)(N_NODES + 1) * 4);
    int*   cursor  = (int*)alloc((size_t)N_NODES * 4);
    int*   bsum    = (int*)alloc((size_t)SCAN_NB * 4);
    int*   boff    = (int*)alloc((size_t)SCAN_NB * 4);
    int*   csr_src = (int*)alloc((size_t)N_EDGES * 4);
    u16*   W1s     = (u16*)alloc((size_t)16 * 256 * 32 * 2);
    u16*   W2s     = (u16*)alloc((size_t)8 * 64 * 32 * 2);
    u16*   h_bf    = (u16*)alloc((size_t)N_NODES * 64 * 2);
    u16*   zsA     = (u16*)alloc((size_t)N_NODES * 64 * 2);
    int*   row32   = (int*)alloc((size_t)N_EDGES * 4);  // aliased as zsB after fill
    int*   col32   = (int*)alloc((size_t)N_EDGES * 4);
    u16*   zsB     = (u16*)row32;  // row32 dead after k_fill2; N_EDGES*4 == N*64*2

    hipMemsetAsync(deg, 0, (size_t)N_NODES * 4, stream);
    k_detect<<<1, 64, 0, stream>>>((const unsigned int*)edges, flag);
    k_convert_count<<<(N_EDGES + 255) / 256, 256, 0, stream>>>(edges, flag, row32, col32, deg);
    k_scan_part<<<SCAN_NB, SCAN_BS, 0, stream>>>(deg, ptr, bsum);
    k_scan_bsum<<<1, 256, 0, stream>>>(bsum, boff, ptr);
    k_scan_apply<<<SCAN_NB, SCAN_BS, 0, stream>>>(deg, boff, ptr, cursor, dinv);
    k_fill2<<<8 * FILL_SLICES, 256, 0, stream>>>(row32, col32, cursor, csr_src);
    k_wconv1<<<(16 * 256 * 32 + 255) / 256, 256, 0, stream>>>(W1, W1s);
    k_wconv2<<<(8 * 64 * 32 + 255) / 256, 256, 0, stream>>>(W2, W2s);
    k_mlp<<<(N_NODES + MLP_ROWS - 1) / MLP_ROWS, 256, 0, stream>>>(x, W1s, b1, W2s, b2,
                                                                   dinv, h_bf, zsA);

    const u16* zin = zsA;
    u16* zout = zsB;
    for (int k = 0; k < KITER; ++k) {
        int last = (k == KITER - 1) ? 1 : 0;
        k_prop3<<<(N_NODES + 3) / 4, 256, 0, stream>>>(zin, h_bf, dinv, ptr, csr_src,
                                                       zout, out, last);
        u16* t = zout;
        zout = (u16*)zin;
        zin = t;
    }
}

// Round 7
// 916.241 us; speedup vs baseline: 1.0714x; 1.0714x over previous
//
#include <hip/hip_runtime.h>
#include <hip/hip_bf16.h>

#define N_NODES 100000
#define N_EDGES 3200000
#define KITER   10
#define ALPHA   0.1f

#define SCAN_BS 512
#define SCAN_NB ((N_NODES + SCAN_BS - 1) / SCAN_BS)   // 196

typedef __attribute__((ext_vector_type(4))) float f32x4;
typedef __attribute__((ext_vector_type(8))) short bf16x8;
typedef unsigned short u16;
typedef unsigned int u32;

__device__ inline float bf2f(u16 u) {
    unsigned int x = ((unsigned int)u) << 16;
    return __uint_as_float(x);
}
__device__ inline float bf2f_lo(unsigned int w) { return __uint_as_float(w << 16); }
__device__ inline float bf2f_hi(unsigned int w) { return __uint_as_float(w & 0xffff0000u); }
__device__ inline u16 f2bf(float f) {
    __hip_bfloat16 h = __float2bfloat16(f);
    return *reinterpret_cast<u16*>(&h);
}
__device__ inline bf16x8 cvt8(float4 lo, float4 hi) {
    bf16x8 r;
    r[0] = (short)f2bf(lo.x); r[1] = (short)f2bf(lo.y);
    r[2] = (short)f2bf(lo.z); r[3] = (short)f2bf(lo.w);
    r[4] = (short)f2bf(hi.x); r[5] = (short)f2bf(hi.y);
    r[6] = (short)f2bf(hi.z); r[7] = (short)f2bf(hi.w);
    return r;
}
// async global(16B/lane) -> LDS (wave-uniform base + lane*16)
__device__ inline void glds16(const u16* g, u16* l) {
    __builtin_amdgcn_global_load_lds(
        (const __attribute__((address_space(1))) u32*)g,
        (__attribute__((address_space(3))) u32*)l, 16, 0, 0);
}

// edge_index may arrive as int64 (reference dtype) or int32 (harness policy).
__global__ void k_detect(const unsigned int* e32, int* flag) {
    if (threadIdx.x == 0) {
        int is64 = 1;
        for (int i = 0; i < 64; ++i)
            if (e32[2 * i + 1] != 0u) { is64 = 0; break; }
        *flag = is64;
    }
}

__device__ inline int eidx(const void* p, int is64, int i) {
    if (is64) return (int)((const long long*)p)[i];
    return ((const int*)p)[i];
}

// convert edges to int32 row/col arrays AND count in-degrees (fused)
__global__ void k_convert_count(const void* edges, const int* flag,
                                int* row32, int* col32, int* deg) {
    int i = blockIdx.x * 256 + threadIdx.x;
    if (i >= N_EDGES) return;
    int is64 = *flag;
    int r = eidx(edges, is64, i);
    int c = eidx(edges, is64, N_EDGES + i);
    row32[i] = r;
    col32[i] = c;
    atomicAdd(&deg[c], 1);
}

// ---- two-level scan: local scan -> scan of block sums -> apply ----
__global__ __launch_bounds__(SCAN_BS) void k_scan_part(const int* __restrict__ deg,
                                                       int* __restrict__ ptr,
                                                       int* __restrict__ bsum) {
    __shared__ int lds[SCAN_BS];
    int t = threadIdx.x;
    int idx = blockIdx.x * SCAN_BS + t;
    int s = (idx < N_NODES) ? deg[idx] : 0;
    lds[t] = s;
    __syncthreads();
#pragma unroll
    for (int off = 1; off < SCAN_BS; off <<= 1) {
        int v = (t >= off) ? lds[t - off] : 0;
        __syncthreads();
        lds[t] += v;
        __syncthreads();
    }
    if (idx < N_NODES) ptr[idx] = lds[t] - s;     // exclusive local
    if (t == SCAN_BS - 1) bsum[blockIdx.x] = lds[t];
}

__global__ __launch_bounds__(256) void k_scan_bsum(const int* __restrict__ bsum,
                                                   int* __restrict__ boff,
                                                   int* __restrict__ ptr) {
    __shared__ int lds[256];
    int t = threadIdx.x;
    int s = (t < SCAN_NB) ? bsum[t] : 0;
    lds[t] = s;
    __syncthreads();
#pragma unroll
    for (int off = 1; off < 256; off <<= 1) {
        int v = (t >= off) ? lds[t - off] : 0;
        __syncthreads();
        lds[t] += v;
        __syncthreads();
    }
    if (t < SCAN_NB) boff[t] = lds[t] - s;        // exclusive
    if (t == 255) ptr[N_NODES] = lds[t];          // total (== N_EDGES)
}

__global__ __launch_bounds__(SCAN_BS) void k_scan_apply(const int* __restrict__ deg,
                                                        const int* __restrict__ boff,
                                                        int* __restrict__ ptr,
                                                        int* __restrict__ cursor,
                                                        float* __restrict__ dinv) {
    int idx = blockIdx.x * SCAN_BS + threadIdx.x;
    if (idx >= N_NODES) return;
    int p = ptr[idx] + boff[blockIdx.x];
    ptr[idx] = p;
    cursor[idx] = p;
    dinv[idx] = rsqrtf((float)(deg[idx] + 1));    // +1 self loop
}

// XCD-ownership fill: grp = blockIdx%8 owns target range [grp*12500, +12500).
#define FILL_SLICES 128
__global__ __launch_bounds__(256) void k_fill2(const int* __restrict__ row32,
                                               const int* __restrict__ col32,
                                               int* cursor, int* __restrict__ csr_src) {
    int b = blockIdx.x;
    int grp = b & 7;
    int slice = b >> 3;
    int lo = grp * 12500, hi = lo + 12500;
    const int per = (N_EDGES + FILL_SLICES - 1) / FILL_SLICES;  // 25000
    int e0 = slice * per;
    int e1 = min(N_EDGES, e0 + per);
    for (int e = e0 + (int)threadIdx.x; e < e1; e += 256) {
        int c = col32[e];
        if (c >= lo && c < hi) {
            int r = row32[e];
            int p = atomicAdd(&cursor[c], 1);
            csr_src[p] = r;
        }
    }
}

// W1 [500,256] f32 -> W1s bf16 [ks=16][n=256][kk=32] with slot-XOR swizzle:
// within each n-row, 16B slot s (= kk>>3) stored at s ^ ((n>>1)&3).
// K zero-padded to 512. (Source-side swizzle so global_load_lds can stay linear.)
__global__ void k_wconv1(const float* W1, u16* W1s) {
    int idx = blockIdx.x * 256 + threadIdx.x;
    if (idx >= 16 * 256 * 32) return;
    int ks = idx / (256 * 32);
    int rem = idx % (256 * 32);
    int n = rem / 32, kk = rem % 32;
    int k = ks * 32 + kk;
    float v = (k < 500) ? W1[k * 256 + n] : 0.0f;
    int slot = kk >> 3, kl = kk & 7;
    int sslot = slot ^ ((n >> 1) & 3);
    W1s[ks * 8192 + n * 32 + sslot * 8 + kl] = f2bf(v);
}

// W2 [256,64] f32 -> W2s bf16 swizzled [ks=8][n=64][kk=32] (unswizzled slots)
__global__ void k_wconv2(const float* W2, u16* W2s) {
    int idx = blockIdx.x * 256 + threadIdx.x;
    if (idx >= 8 * 64 * 32) return;
    int ks = idx / (64 * 32);
    int rem = idx % (64 * 32);
    int n = rem / 32, kk = rem % 32;
    int k = ks * 32 + kk;
    W2s[idx] = f2bf(W2[k * 64 + n]);
}

// Fused MLP v5 (m97-style): 128x256 tile, 8 waves (2Mx4N), BK=32, 16 steps,
// double-buffered LDS. B staged via global_load_lds (16B) ONCE per block
// (shared by 8 waves). A reg-staged with T14 async split: loads issued before
// the compute phase, cvt+ds_write after (compute phase = pure ds_read+MFMA,
// no vmcnt waits inside). Slot-XOR swizzle on both LDS operands -> 2-way
// bank aliasing (free). One barrier per K-step.
#define MLP2_ROWS 128
#define HSTR 264    // u16 stride for H rows
#define H2STR 72    // u16 stride for pack buffer

__global__ __launch_bounds__(512, 4) void k_mlp2(
    const float* __restrict__ x, const u16* __restrict__ W1s,
    const float* __restrict__ b1, const u16* __restrict__ W2s,
    const float* __restrict__ b2, const float* __restrict__ dinv,
    u16* __restrict__ h_bf, u16* __restrict__ zs0) {

    __shared__ u16 smem[33792];   // 67584 B: K-loop [A 2x4096 | B 2x8192], then H
    u16* Abuf = smem;             // 2 * 4096 u16
    u16* Bbuf = smem + 8192;      // 2 * 8192 u16

    int t = threadIdx.x;
    int lane = t & 63, w = t >> 6;
    int wr = w >> 2, wc = w & 3;
    int cl = lane & 15, hi = lane >> 4;
    int m0 = blockIdx.x * MLP2_ROWS;

    // A staging coords: thread t stages row sr, k-slot skq (8 k's)
    int sr = t >> 2, skq = t & 3;
    int srow = min(m0 + sr, N_NODES - 1);
    const size_t XMAX = (size_t)N_NODES * 500 - 4;  // last valid float4 start
    size_t sbase = (size_t)srow * 500 + skq * 8;
    int sAoff = sr * 32 + ((skq ^ ((sr >> 1) & 3)) << 3);  // swizzled u16 offset

    f32x4 acc[4][4];
    f32x4 zero = {0.f, 0.f, 0.f, 0.f};
#pragma unroll
    for (int nt = 0; nt < 4; ++nt)
#pragma unroll
        for (int i = 0; i < 4; ++i) acc[nt][i] = zero;

    float4 pa, pb;

    // ---- prologue: stage ks=0 into buffer 0 ----
    {
        size_t f = sbase;
        size_t a0 = f > XMAX ? XMAX : f;
        size_t a1 = (f + 4) > XMAX ? XMAX : (f + 4);
        pa = *(const float4*)(x + a0);
        pb = *(const float4*)(x + a1);
        glds16(W1s + (w * 2 + 0) * 512 + lane * 8, Bbuf + (w * 2 + 0) * 512);
        glds16(W1s + (w * 2 + 1) * 512 + lane * 8, Bbuf + (w * 2 + 1) * 512);
        bf16x8 av = cvt8(pa, pb);
        *(bf16x8*)&Abuf[sAoff] = av;
    }
    __syncthreads();

    for (int ks = 0; ks < 16; ++ks) {
        int cur = ks & 1, nxt = cur ^ 1;
        if (ks < 15) {
            // issue next-step loads EARLY (T14): A->regs, B->LDS(next)
            size_t f = sbase + (size_t)(ks + 1) * 32;
            size_t a0 = f > XMAX ? XMAX : f;
            size_t a1 = (f + 4) > XMAX ? XMAX : (f + 4);
            pa = *(const float4*)(x + a0);
            pb = *(const float4*)(x + a1);
            const u16* bsrc = W1s + (ks + 1) * 8192;
            glds16(bsrc + (w * 2 + 0) * 512 + lane * 8,
                   Bbuf + nxt * 8192 + (w * 2 + 0) * 512);
            glds16(bsrc + (w * 2 + 1) * 512 + lane * 8,
                   Bbuf + nxt * 8192 + (w * 2 + 1) * 512);
        }
        // ---- compute on cur: pure ds_read + MFMA ----
        const u16* Ab = Abuf + cur * 4096;
        const u16* Bb = Bbuf + cur * 8192;
        bf16x8 af[4];
#pragma unroll
        for (int i = 0; i < 4; ++i) {
            int row = wr * 64 + i * 16 + cl;
            af[i] = *(const bf16x8*)&Ab[row * 32 + ((hi ^ ((row >> 1) & 3)) << 3)];
        }
#pragma unroll
        for (int nt = 0; nt < 4; ++nt) {
            int n = wc * 64 + nt * 16 + cl;
            bf16x8 bv = *(const bf16x8*)&Bb[n * 32 + ((hi ^ ((n >> 1) & 3)) << 3)];
#pragma unroll
            for (int i = 0; i < 4; ++i)
                acc[nt][i] = __builtin_amdgcn_mfma_f32_16x16x32_bf16(af[i], bv, acc[nt][i], 0, 0, 0);
        }
        if (ks < 15) {
            // write A(next) LATE (vmcnt wait lands here, after the MFMAs)
            bf16x8 av = cvt8(pa, pb);
            *(bf16x8*)&Abuf[nxt * 4096 + sAoff] = av;
        }
        __syncthreads();
    }

    // ---- epilogue 1: +b1, relu -> H (smem reused; K-loop bufs dead) ----
    u16* H = smem;
#pragma unroll
    for (int nt = 0; nt < 4; ++nt) {
        int col = wc * 64 + nt * 16 + cl;
        float bb = b1[col];
#pragma unroll
        for (int i = 0; i < 4; ++i) {
            int row = wr * 64 + i * 16 + hi * 4;
#pragma unroll
            for (int r = 0; r < 4; ++r)
                H[(row + r) * HSTR + col] = f2bf(fmaxf(acc[nt][i][r] + bb, 0.0f));
        }
    }
    __syncthreads();

    // ---- GEMM2: wave w handles rows w*16..+15; W2s direct from global ----
    f32x4 acc2[4];
#pragma unroll
    for (int i = 0; i < 4; ++i) acc2[i] = zero;
    int rA0 = w * 16 + cl;
#pragma unroll
    for (int ks2 = 0; ks2 < 8; ++ks2) {
        bf16x8 afv = *(const bf16x8*)&H[rA0 * HSTR + ks2 * 32 + 8 * hi];
#pragma unroll
        for (int nt = 0; nt < 4; ++nt) {
            bf16x8 bv = *(const bf16x8*)(W2s + (ks2 * 64 + nt * 16 + cl) * 32 + 8 * hi);
            acc2[nt] = __builtin_amdgcn_mfma_f32_16x16x32_bf16(afv, bv, acc2[nt], 0, 0, 0);
        }
    }
    __syncthreads();   // H dead; reuse as pack buffer

    // ---- epilogue 2: +b2 -> H2 ----
    u16* H2 = smem;
    {
        int rl0 = w * 16 + hi * 4;
#pragma unroll
        for (int nt = 0; nt < 4; ++nt) {
            int col = nt * 16 + cl;
            float bb = b2[col];
#pragma unroll
            for (int r = 0; r < 4; ++r)
                H2[(rl0 + r) * H2STR + col] = f2bf(acc2[nt][r] + bb);
        }
    }
    __syncthreads();

    // ---- pack & store: thread t handles a quarter row (16 u16 = 32B) ----
    {
        int rl = t >> 2, q = t & 3;
        int grow = m0 + rl;
        if (grow < N_NODES) {
            float dv = dinv[grow];
            const uint4* src = (const uint4*)&H2[rl * H2STR + q * 16];
            uint4 hq[2] = {src[0], src[1]};
            uint4 zq[2];
#pragma unroll
            for (int i = 0; i < 2; ++i) {
                unsigned int* hw = (unsigned int*)&hq[i];
                unsigned int* zw = (unsigned int*)&zq[i];
#pragma unroll
                for (int jj = 0; jj < 4; ++jj) {
                    float lo = dv * bf2f_lo(hw[jj]);
                    float hi2 = dv * bf2f_hi(hw[jj]);
                    zw[jj] = (unsigned)f2bf(lo) | ((unsigned)f2bf(hi2) << 16);
                }
            }
            uint4* hd = (uint4*)(h_bf + (size_t)grow * 64 + q * 16);
            uint4* zd = (uint4*)(zs0 + (size_t)grow * 64 + q * 16);
            hd[0] = hq[0]; hd[1] = hq[1];
            zd[0] = zq[0]; zd[1] = zq[1];
        }
    }
}

// Propagation v3 (unchanged): one wave per node, dwordx4 gathers of 8 edges.
__global__ __launch_bounds__(256) void k_prop3(
    const u16* __restrict__ zs_in, const u16* __restrict__ h_bf,
    const float* __restrict__ dinv, const int* __restrict__ ptr,
    const int* __restrict__ csr_src, u16* __restrict__ zs_out,
    float* __restrict__ out, int last) {

    int lane = threadIdx.x & 63;
    int g = lane >> 3;   // edge slot 0..7
    int c = lane & 7;    // channels 8c..8c+7
    int v = blockIdx.x * 4 + (threadIdx.x >> 6);
    if (v >= N_NODES) return;
    int s0 = ptr[v], s1 = ptr[v + 1];

    float a0 = 0.f, a1 = 0.f, a2 = 0.f, a3 = 0.f;
    float a4 = 0.f, a5 = 0.f, a6 = 0.f, a7 = 0.f;
    float b0 = 0.f, b1 = 0.f, b2 = 0.f, b3 = 0.f;
    float b4 = 0.f, b5 = 0.f, b6 = 0.f, b7 = 0.f;

    for (int base = s0; base < s1; base += 64) {
        int nwin = min(64, s1 - base);
        int ei = base + lane;
        int sv = (ei < s1) ? csr_src[ei] : v;   // fallback: safe address
        int j = 0;
        for (; j + 16 <= nwin; j += 16) {
            int u0 = __shfl(sv, j + g, 64);
            int u1 = __shfl(sv, j + 8 + g, 64);
            uint4 q0 = *(const uint4*)(zs_in + (size_t)u0 * 64 + c * 8);
            uint4 q1 = *(const uint4*)(zs_in + (size_t)u1 * 64 + c * 8);
            a0 += bf2f_lo(q0.x); a1 += bf2f_hi(q0.x);
            a2 += bf2f_lo(q0.y); a3 += bf2f_hi(q0.y);
            a4 += bf2f_lo(q0.z); a5 += bf2f_hi(q0.z);
            a6 += bf2f_lo(q0.w); a7 += bf2f_hi(q0.w);
            b0 += bf2f_lo(q1.x); b1 += bf2f_hi(q1.x);
            b2 += bf2f_lo(q1.y); b3 += bf2f_hi(q1.y);
            b4 += bf2f_lo(q1.z); b5 += bf2f_hi(q1.z);
            b6 += bf2f_lo(q1.w); b7 += bf2f_hi(q1.w);
        }
        for (; j < nwin; j += 8) {
            int idx = j + g;
            int u = __shfl(sv, idx, 64);  // idx<=63; invalid lanes hold v (safe)
            uint4 q = *(const uint4*)(zs_in + (size_t)u * 64 + c * 8);
            if (idx < nwin) {
                a0 += bf2f_lo(q.x); a1 += bf2f_hi(q.x);
                a2 += bf2f_lo(q.y); a3 += bf2f_hi(q.y);
                a4 += bf2f_lo(q.z); a5 += bf2f_hi(q.z);
                a6 += bf2f_lo(q.w); a7 += bf2f_hi(q.w);
            }
        }
    }
    a0 += b0; a1 += b1; a2 += b2; a3 += b3;
    a4 += b4; a5 += b5; a6 += b6; a7 += b7;
#pragma unroll
    for (int off = 8; off <= 32; off <<= 1) {
        a0 += __shfl_xor(a0, off, 64); a1 += __shfl_xor(a1, off, 64);
        a2 += __shfl_xor(a2, off, 64); a3 += __shfl_xor(a3, off, 64);
        a4 += __shfl_xor(a4, off, 64); a5 += __shfl_xor(a5, off, 64);
        a6 += __shfl_xor(a6, off, 64); a7 += __shfl_xor(a7, off, 64);
    }

    float dv = dinv[v];
    uint4 qs = *(const uint4*)(zs_in + (size_t)v * 64 + c * 8);
    uint4 qh = *(const uint4*)(h_bf + (size_t)v * 64 + c * 8);
    float z0 = (1.0f - ALPHA) * dv * (a0 + bf2f_lo(qs.x)) + ALPHA * bf2f_lo(qh.x);
    float z1 = (1.0f - ALPHA) * dv * (a1 + bf2f_hi(qs.x)) + ALPHA * bf2f_hi(qh.x);
    float z2 = (1.0f - ALPHA) * dv * (a2 + bf2f_lo(qs.y)) + ALPHA * bf2f_lo(qh.y);
    float z3 = (1.0f - ALPHA) * dv * (a3 + bf2f_hi(qs.y)) + ALPHA * bf2f_hi(qh.y);
    float z4 = (1.0f - ALPHA) * dv * (a4 + bf2f_lo(qs.z)) + ALPHA * bf2f_lo(qh.z);
    float z5 = (1.0f - ALPHA) * dv * (a5 + bf2f_hi(qs.z)) + ALPHA * bf2f_hi(qh.z);
    float z6 = (1.0f - ALPHA) * dv * (a6 + bf2f_lo(qs.w)) + ALPHA * bf2f_lo(qh.w);
    float z7 = (1.0f - ALPHA) * dv * (a7 + bf2f_hi(qs.w)) + ALPHA * bf2f_hi(qh.w);

    if (!last) {
        if (g == 0) {
            uint4 o;
            o.x = (unsigned)f2bf(dv * z0) | ((unsigned)f2bf(dv * z1) << 16);
            o.y = (unsigned)f2bf(dv * z2) | ((unsigned)f2bf(dv * z3) << 16);
            o.z = (unsigned)f2bf(dv * z4) | ((unsigned)f2bf(dv * z5) << 16);
            o.w = (unsigned)f2bf(dv * z6) | ((unsigned)f2bf(dv * z7) << 16);
            *(uint4*)(zs_out + (size_t)v * 64 + c * 8) = o;
        }
    } else {
        float m = fmaxf(fmaxf(fmaxf(z0, z1), fmaxf(z2, z3)),
                        fmaxf(fmaxf(z4, z5), fmaxf(z6, z7)));
#pragma unroll
        for (int off = 1; off <= 4; off <<= 1) m = fmaxf(m, __shfl_xor(m, off, 64));
        float p = expf(z0 - m) + expf(z1 - m) + expf(z2 - m) + expf(z3 - m)
                + expf(z4 - m) + expf(z5 - m) + expf(z6 - m) + expf(z7 - m);
#pragma unroll
        for (int off = 1; off <= 4; off <<= 1) p += __shfl_xor(p, off, 64);
        float ls = logf(p);
        if (g == 0) {
            float4 o1 = {z0 - m - ls, z1 - m - ls, z2 - m - ls, z3 - m - ls};
            float4 o2 = {z4 - m - ls, z5 - m - ls, z6 - m - ls, z7 - m - ls};
            *(float4*)(out + (size_t)v * 64 + c * 8) = o1;
            *(float4*)(out + (size_t)v * 64 + c * 8 + 4) = o2;
        }
    }
}

extern "C" void kernel_launch(void* const* d_in, const int* in_sizes, int n_in,
                              void* d_out, int out_size, void* d_ws, size_t ws_size,
                              hipStream_t stream) {
    const float* x  = (const float*)d_in[0];
    const void* edges = d_in[1];
    const float* W1 = (const float*)d_in[2];
    const float* b1 = (const float*)d_in[3];
    const float* W2 = (const float*)d_in[4];
    const float* b2 = (const float*)d_in[5];
    float* out = (float*)d_out;

    char* ws = (char*)d_ws;
    size_t off = 0;
    auto alloc = [&](size_t bytes) -> void* {
        void* p = ws + off;
        off = (off + bytes + 255) & ~(size_t)255;
        return p;
    };
    int*   flag    = (int*)alloc(4);
    int*   deg     = (int*)alloc((size_t)N_NODES * 4);
    float* dinv    = (float*)alloc((size_t)N_NODES * 4);
    int*   ptr     = (int*)alloc((size_t)(N_NODES + 1) * 4);
    int*   cursor  = (int*)alloc((size_t)N_NODES * 4);
    int*   bsum    = (int*)alloc((size_t)SCAN_NB * 4);
    int*   boff    = (int*)alloc((size_t)SCAN_NB * 4);
    int*   csr_src = (int*)alloc((size_t)N_EDGES * 4);
    u16*   W1s     = (u16*)alloc((size_t)16 * 256 * 32 * 2);
    u16*   W2s     = (u16*)alloc((size_t)8 * 64 * 32 * 2);
    u16*   h_bf    = (u16*)alloc((size_t)N_NODES * 64 * 2);
    u16*   zsA     = (u16*)alloc((size_t)N_NODES * 64 * 2);
    int*   row32   = (int*)alloc((size_t)N_EDGES * 4);  // aliased as zsB after fill
    int*   col32   = (int*)alloc((size_t)N_EDGES * 4);
    u16*   zsB     = (u16*)row32;  // row32 dead after k_fill2; N_EDGES*4 == N*64*2

    hipMemsetAsync(deg, 0, (size_t)N_NODES * 4, stream);
    k_detect<<<1, 64, 0, stream>>>((const unsigned int*)edges, flag);
    k_convert_count<<<(N_EDGES + 255) / 256, 256, 0, stream>>>(edges, flag, row32, col32, deg);
    k_scan_part<<<SCAN_NB, SCAN_BS, 0, stream>>>(deg, ptr, bsum);
    k_scan_bsum<<<1, 256, 0, stream>>>(bsum, boff, ptr);
    k_scan_apply<<<SCAN_NB, SCAN_BS, 0, stream>>>(deg, boff, ptr, cursor, dinv);
    k_fill2<<<8 * FILL_SLICES, 256, 0, stream>>>(row32, col32, cursor, csr_src);
    k_wconv1<<<(16 * 256 * 32 + 255) / 256, 256, 0, stream>>>(W1, W1s);
    k_wconv2<<<(8 * 64 * 32 + 255) / 256, 256, 0, stream>>>(W2, W2s);
    k_mlp2<<<(N_NODES + MLP2_ROWS - 1) / MLP2_ROWS, 512, 0, stream>>>(x, W1s, b1, W2s, b2,
                                                                      dinv, h_bf, zsA);

    const u16* zin = zsA;
    u16* zout = zsB;
    for (int k = 0; k < KITER; ++k) {
        int last = (k == KITER - 1) ? 1 : 0;
        k_prop3<<<(N_NODES + 3) / 4, 256, 0, stream>>>(zin, h_bf, dinv, ptr, csr_src,
                                                       zout, out, last);
        u16* t = zout;
        zout = (u16*)zin;
        zin = t;
    }
}